// Round 7
// baseline (580.349 us; speedup 1.0000x reference)
//
#include <hip/hip_runtime.h>
#include <hip/hip_bf16.h>

// CapsModel: B=64 N=32 H=W=16 A=16 K=3 stride=2 -> Ho=Wo=7, M=32, SD=4, D=16
// conv routing: 2 sites/block, 256 thr (32 m-lanes x 8 nkl-groups),
//               TWO sites per thread: one w-load feeds both sites (halves
//               strided-L2 w traffic, doubles prefetch distance).
//               launch_bounds(256,1): loose VGPR cap -> no spills
//               (R4's (256,3) made the compiler pick 84 VGPR and spill 138MB;
//                R5's (512,4) forced 64 VGPR and spilled 56MB).
// fc routing:   pass-split kernels: partial (512 blocks) + combine/LN (64).
// No-max softmax (|logit| <~1, exp safe in fp32).

#define LN_EPS 1e-5f

// ---------------- weight transposes ----------------
// wT [288][32][16]: row r = n*9+kl (n-major, matches s_inp), wT[(r*32+m)*16+xd]
__global__ __launch_bounds__(256) void transpose_wconv(
    const float* __restrict__ wconv, float* __restrict__ wT)
{
    const int i = blockIdx.x * 256 + threadIdx.x;
    if (i < 147456) {
        const int xd = i & 15, mm = (i >> 4) & 31, r = i >> 9;   // r = n*9+kl
        const int n = r / 9, kl = r % 9;
        wT[i] = wconv[((kl * 32 + n) * 16 + xd) * 32 + mm];
    }
}

// wT2b [1568][16][16]: [n][m (pad 10->16, zeros)][x*4+d]
__global__ __launch_bounds__(256) void transpose_wfc(
    const float* __restrict__ wfc, float* __restrict__ wT2b)
{
    const int j = blockIdx.x * 256 + threadIdx.x;
    if (j < 401408) {
        const int xd = j & 15, mm = (j >> 4) & 15, n = j >> 8;
        const int x = xd >> 2, dd = xd & 3;
        wT2b[j] = (mm < 10) ? wfc[((n * 4 + x) * 4 + dd) * 10 + mm] : 0.f;
    }
}

// ---------------- Stage 1: conv routing ----------------
__global__ __launch_bounds__(256, 1) void conv_routing_kernel(
    const float* __restrict__ x,      // [64][32][16][16][16]
    const float* __restrict__ wT,     // [288][32][16], row = n*9+kl
    const float* __restrict__ ln1g,
    const float* __restrict__ ln1b,
    const int*   __restrict__ nroute,
    float* __restrict__ vout)         // [64][32][49][16]
{
    __shared__ float s_inp[2][288][16];     // 36 KB, row = n*9+kl
    __shared__ float s_v[2][32][16];        // 4 KB
    __shared__ float s_red[3][2][32][16];   // 12 KB (waves 1..3 partials)

    const int tid   = threadIdx.x;
    const int m     = tid & 31;
    const int g     = tid >> 5;     // 0..7
    const int wvi   = tid >> 6;     // 0..3
    const int hmask = tid & 32;
    const int site0 = blockIdx.x * 2;

    // stage inp for both sites (float4, coalesced); row = n*9+kl
    for (int i = tid; i < 2304; i += 256) {
        const int s = (i >= 1152) ? 1 : 0;
        const int j = s ? i - 1152 : i;
        const int row = j >> 2, q = j & 3;
        const int site = site0 + s;
        const int b = site / 49, hw = site % 49;
        const int h = hw / 7, w = hw % 7;
        const int n = row / 9, kl = row % 9;
        const int k = kl / 3, l = kl % 3;
        const float4 val = *(const float4*)(
            x + ((((b * 32 + n) * 16 + (2 * h + k)) * 16 + (2 * w + l)) * 16 + q * 4));
        *(float4*)(&s_inp[s][row][q * 4]) = val;
    }
    __syncthreads();

    const int R = *nroute;
    const int nkl0 = g * 36;
    const float* const wp0 = wT + (nkl0 * 32 + m) * 16;

#define LDW(dst, p)                                                    \
    {                                                                  \
        _Pragma("unroll") for (int q = 0; q < 4; ++q)                  \
            *(float4*)(&(dst)[q * 4]) = *(const float4*)((p) + q * 4); \
    }

    for (int pass = 0; pass < R; ++pass) {
        float vn0[16], vn1[16];
#pragma unroll
        for (int i = 0; i < 16; ++i) { vn0[i] = 0.f; vn1[i] = 0.f; }
        float vc0[16], vc1[16];
        if (pass) {
#pragma unroll
            for (int q = 0; q < 4; ++q) {
                *(float4*)(&vc0[q * 4]) = *(const float4*)(&s_v[0][m][q * 4]);
                *(float4*)(&vc1[q * 4]) = *(const float4*)(&s_v[1][m][q * 4]);
            }
        }

        // pass-0 body: pure accumulate (both sites off one w fragment)
        auto body0 = [&](int t, const float* wv) {
            const int nkl = nkl0 + t;
#pragma unroll
            for (int s = 0; s < 2; ++s) {
                float in_[16];
#pragma unroll
                for (int q = 0; q < 4; ++q)
                    *(float4*)(&in_[q * 4]) = *(const float4*)(&s_inp[s][nkl][q * 4]);
                float* vn = s ? vn1 : vn0;
#pragma unroll
                for (int a = 0; a < 4; ++a) {
#pragma unroll
                    for (int d = 0; d < 4; ++d) {
                        float acc = in_[a * 4 + 0] * wv[0 + d];
                        acc = fmaf(in_[a * 4 + 1], wv[4 + d], acc);
                        acc = fmaf(in_[a * 4 + 2], wv[8 + d], acc);
                        acc = fmaf(in_[a * 4 + 3], wv[12 + d], acc);
                        vn[a * 4 + d] += acc;
                    }
                }
            }
        };

        // routing body: votes -> logit (tree dot) -> no-max softmax -> accum
        auto body1 = [&](int t, const float* wv) {
            const int nkl = nkl0 + t;
#pragma unroll
            for (int s = 0; s < 2; ++s) {
                float in_[16];
#pragma unroll
                for (int q = 0; q < 4; ++q)
                    *(float4*)(&in_[q * 4]) = *(const float4*)(&s_inp[s][nkl][q * 4]);
                float uh[16];
#pragma unroll
                for (int a = 0; a < 4; ++a) {
#pragma unroll
                    for (int d = 0; d < 4; ++d) {
                        float acc = in_[a * 4 + 0] * wv[0 + d];
                        acc = fmaf(in_[a * 4 + 1], wv[4 + d], acc);
                        acc = fmaf(in_[a * 4 + 2], wv[8 + d], acc);
                        acc = fmaf(in_[a * 4 + 3], wv[12 + d], acc);
                        uh[a * 4 + d] = acc;
                    }
                }
                const float* vc = s ? vc1 : vc0;
                float* vn = s ? vn1 : vn0;
                // tree-reduced dot: 4 independent fma chains of depth 4
                float l0 = uh[0] * vc[0], l1 = uh[1] * vc[1];
                float l2 = uh[2] * vc[2], l3 = uh[3] * vc[3];
#pragma unroll
                for (int i = 4; i < 16; i += 4) {
                    l0 = fmaf(uh[i + 0], vc[i + 0], l0);
                    l1 = fmaf(uh[i + 1], vc[i + 1], l1);
                    l2 = fmaf(uh[i + 2], vc[i + 2], l2);
                    l3 = fmaf(uh[i + 3], vc[i + 3], l3);
                }
                const float lg = ((l0 + l1) + (l2 + l3)) * 0.25f;
                const float e = __expf(lg);
                float sm = e;
#pragma unroll
                for (int off = 16; off >= 1; off >>= 1)
                    sm += __shfl_xor(sm, off, 32);
                const float qk = e * __builtin_amdgcn_rcpf(sm * (1.f + 1e-10f));
#pragma unroll
                for (int i = 0; i < 16; ++i) vn[i] = fmaf(qk, uh[i], vn[i]);
            }
        };

        // K-loop, unroll 2 with double-buffered w prefetch; tail peeled.
        {
            const float* wp = wp0;
            float wA[16], wB[16];
            LDW(wA, wp);
            if (pass == 0) {
                for (int t2 = 0; t2 < 17; ++t2) {
                    const int t = t2 * 2;
                    LDW(wB, wp + 512);
                    body0(t, wA);
                    LDW(wA, wp + 1024);
                    body0(t + 1, wB);
                    wp += 1024;
                }
                LDW(wB, wp + 512);
                body0(34, wA);
                body0(35, wB);
            } else {
                for (int t2 = 0; t2 < 17; ++t2) {
                    const int t = t2 * 2;
                    LDW(wB, wp + 512);
                    body1(t, wA);
                    LDW(wA, wp + 1024);
                    body1(t + 1, wB);
                    wp += 1024;
                }
                LDW(wB, wp + 512);
                body1(34, wA);
                body1(35, wB);
            }
        }

        // pre-reduce the 2 g's within each wave
#pragma unroll
        for (int i = 0; i < 16; ++i) {
            vn0[i] += __shfl_xor(vn0[i], 32, 64);
            vn1[i] += __shfl_xor(vn1[i], 32, 64);
        }
        if (wvi > 0 && hmask == 0) {
#pragma unroll
            for (int q = 0; q < 4; ++q) {
                *(float4*)(&s_red[wvi - 1][0][m][q * 4]) = *(float4*)(&vn0[q * 4]);
                *(float4*)(&s_red[wvi - 1][1][m][q * 4]) = *(float4*)(&vn1[q * 4]);
            }
        }
        __syncthreads();

        if (wvi == 0 && hmask == 0) {
#pragma unroll
            for (int j = 0; j < 3; ++j) {
#pragma unroll
                for (int i = 0; i < 16; ++i) {
                    vn0[i] += s_red[j][0][m][i];
                    vn1[i] += s_red[j][1][m][i];
                }
            }
            const float scale = pass ? 1.f : (1.f / 32.f);
#pragma unroll
            for (int s = 0; s < 2; ++s) {
                float* vv = s ? vn1 : vn0;
                float mu = 0.f;
#pragma unroll
                for (int i = 0; i < 16; ++i) { vv[i] *= scale; mu += vv[i]; }
                mu *= (1.f / 16.f);
                float var = 0.f;
#pragma unroll
                for (int i = 0; i < 16; ++i) {
                    const float d0 = vv[i] - mu;
                    var = fmaf(d0, d0, var);
                }
                var *= (1.f / 16.f);
                const float inv = rsqrtf(var + LN_EPS);
#pragma unroll
                for (int i = 0; i < 16; ++i)
                    s_v[s][m][i] = (vv[i] - mu) * inv * ln1g[i] + ln1b[i];
            }
        }
        __syncthreads();
    }

    // write v: 256 float4
    {
        const int p = tid;
        const int s = p >> 7, mm = (p >> 2) & 31, q = p & 3;
        const int site = site0 + s;
        const int b = site / 49, hw = site % 49;
        const float4 val = *(const float4*)(&s_v[s][mm][q * 4]);
        *(float4*)(vout + ((b * 32 + mm) * 49 + hw) * 16 + q * 4) = val;
    }
}

// ---------------- Stage 2: FC routing (pass-split) ----------------
// fc_partial: 512 blocks = 64 b x 8 chunks; 256 thr = 16 grp x 16 ml.
__global__ __launch_bounds__(256, 4) void fc_partial(
    const float* __restrict__ fcin,  // [64][1568][16]
    const float* __restrict__ wT2b,  // [1568][16][16] ([n][ml][x*4+d])
    const float* __restrict__ u,     // [64][16][16] ([b][ml][ad])
    const int*   __restrict__ nroute,
    const int    pass,
    float* __restrict__ partial)     // [512][16][16]
{
    __shared__ float s_red[4][16][17];

    const int R = *nroute;
    if (pass >= R) return;
    const int blk = blockIdx.x;
    const int b = blk >> 3, c = blk & 7;
    const int tid = threadIdx.x;
    const int ml = tid & 15, grp = tid >> 4;   // grp 0..15
    const int wv = tid >> 6;
    const float* fb = fcin + (b * 1568 + c * 196) * 16;
    const float* wb = wT2b + (c * 196 * 16) * 16;

    float un[16];
#pragma unroll
    for (int i = 0; i < 16; ++i) un[i] = 0.f;
    float ur[16];
    if (pass) {
#pragma unroll
        for (int q = 0; q < 4; ++q)
            *(float4*)(&ur[q * 4]) = *(const float4*)(u + (b * 16 + ml) * 16 + q * 4);
    }

    for (int t = 0; t < 13; ++t) {
        const int off = t * 16 + grp;
        if (off >= 196) break;   // uniform within each 16-lane cluster
        float iv[16], wv_[16];
        const float* ip = fb + off * 16;
        const float* wp = wb + (off * 16 + ml) * 16;
#pragma unroll
        for (int q = 0; q < 4; ++q) {
            *(float4*)(&iv[q * 4]) = *(const float4*)(ip + q * 4);
            *(float4*)(&wv_[q * 4]) = *(const float4*)(wp + q * 4);
        }
        float vote[16];
#pragma unroll
        for (int a = 0; a < 4; ++a) {
#pragma unroll
            for (int d = 0; d < 4; ++d) {
                float acc = iv[a * 4 + 0] * wv_[0 + d];
                acc = fmaf(iv[a * 4 + 1], wv_[4 + d], acc);
                acc = fmaf(iv[a * 4 + 2], wv_[8 + d], acc);
                acc = fmaf(iv[a * 4 + 3], wv_[12 + d], acc);
                vote[a * 4 + d] = acc;
            }
        }
        if (pass == 0) {
#pragma unroll
            for (int i = 0; i < 16; ++i) un[i] += vote[i];
        } else {
            float l0 = vote[0] * ur[0], l1 = vote[1] * ur[1];
            float l2 = vote[2] * ur[2], l3 = vote[3] * ur[3];
#pragma unroll
            for (int i = 4; i < 16; i += 4) {
                l0 = fmaf(vote[i + 0], ur[i + 0], l0);
                l1 = fmaf(vote[i + 1], ur[i + 1], l1);
                l2 = fmaf(vote[i + 2], ur[i + 2], l2);
                l3 = fmaf(vote[i + 3], ur[i + 3], l3);
            }
            const float lg = ((l0 + l1) + (l2 + l3)) * 0.25f;
            float e = __expf(lg);
            if (ml >= 10) e = 0.f;
            float sm = e;
#pragma unroll
            for (int off2 = 8; off2 >= 1; off2 >>= 1)
                sm += __shfl_xor(sm, off2, 16);
            const float qk = e * __builtin_amdgcn_rcpf(sm * (1.f + 1e-10f));
#pragma unroll
            for (int i = 0; i < 16; ++i) un[i] = fmaf(qk, vote[i], un[i]);
        }
    }

    // sum the 4 grps within each wave
#pragma unroll
    for (int i = 0; i < 16; ++i) {
        un[i] += __shfl_xor(un[i], 16, 64);
        un[i] += __shfl_xor(un[i], 32, 64);
    }
    if ((tid & 63) < 16) {
#pragma unroll
        for (int i = 0; i < 16; ++i) s_red[wv][ml][i] = un[i];
    }
    __syncthreads();

    // 256 threads: (mlf, i) -> sum 4 waves, write partial
    {
        const int mlf = tid >> 4, i = tid & 15;
        const float s = s_red[0][mlf][i] + s_red[1][mlf][i]
                      + s_red[2][mlf][i] + s_red[3][mlf][i];
        partial[(blk * 16 + mlf) * 16 + i] = s;
    }
}

// fc_combine: 64 blocks x 256 thr; thread = (ml = tid>>4, i = tid&15).
__global__ __launch_bounds__(256) void fc_combine(
    const float* __restrict__ partial,  // [512][16][16]
    const float* __restrict__ ln2g,
    const float* __restrict__ ln2b,
    const int*   __restrict__ nroute,
    const int    pass,
    float* __restrict__ u,              // [64][16][16]
    float* __restrict__ out)            // [64][10][16]
{
    const int R = *nroute;
    if (pass >= R) return;
    const int b = blockIdx.x;
    const int tid = threadIdx.x;
    const int i = tid & 15, ml = tid >> 4;

    float s = 0.f;
#pragma unroll
    for (int c = 0; c < 8; ++c)
        s += partial[((b * 8 + c) * 16 + ml) * 16 + i];
    if (pass == 0) s *= 0.1f;

    // LN over the 16 i-lanes of this cluster
    float mu = s;
#pragma unroll
    for (int off = 8; off >= 1; off >>= 1) mu += __shfl_xor(mu, off, 16);
    mu *= (1.f / 16.f);
    const float d0 = s - mu;
    float var = d0 * d0;
#pragma unroll
    for (int off = 8; off >= 1; off >>= 1) var += __shfl_xor(var, off, 16);
    var *= (1.f / 16.f);
    const float r = (s - mu) * rsqrtf(var + LN_EPS) * ln2g[i] + ln2b[i];

    u[(b * 16 + ml) * 16 + i] = r;
    if (pass == R - 1 && ml < 10) out[(b * 10 + ml) * 16 + i] = r;
}

extern "C" void kernel_launch(void* const* d_in, const int* in_sizes, int n_in,
                              void* d_out, int out_size, void* d_ws, size_t ws_size,
                              hipStream_t stream) {
    const float* x     = (const float*)d_in[0];
    const float* wconv = (const float*)d_in[1];
    const float* wfc   = (const float*)d_in[2];
    const float* ln1g  = (const float*)d_in[3];
    const float* ln1b  = (const float*)d_in[4];
    const float* ln2g  = (const float*)d_in[5];
    const float* ln2b  = (const float*)d_in[6];
    const int*   nrt   = (const int*)d_in[7];

    float* vout    = (float*)d_ws;                               // 6,422,528 B
    // wT (589,824 B) and wT2b (1,605,632 B) share this region (sequenced).
    float* wT      = (float*)((char*)d_ws + 6422528);
    float* wT2b    = (float*)((char*)d_ws + 6422528);
    float* ubuf    = (float*)((char*)d_ws + 8028160);            // 65,536 B
    float* partial = (float*)((char*)d_ws + 8093696);            // 524,288 B
    float* out     = (float*)d_out;

    hipLaunchKernelGGL(transpose_wconv, dim3(576), dim3(256), 0, stream,
                       wconv, wT);
    hipLaunchKernelGGL(conv_routing_kernel, dim3(1568), dim3(256), 0, stream,
                       x, wT, ln1g, ln1b, nrt, vout);
    hipLaunchKernelGGL(transpose_wfc, dim3(1568), dim3(256), 0, stream,
                       wfc, wT2b);
    for (int pass = 0; pass < 3; ++pass) {
        hipLaunchKernelGGL(fc_partial, dim3(512), dim3(256), 0, stream,
                           vout, wT2b, ubuf, nrt, pass, partial);
        hipLaunchKernelGGL(fc_combine, dim3(64), dim3(256), 0, stream,
                           partial, ln2g, ln2b, nrt, pass, ubuf, out);
    }
}

// Round 8
// 428.076 us; speedup vs baseline: 1.3557x; 1.3557x over previous
//
#include <hip/hip_runtime.h>
#include <hip/hip_bf16.h>

// CapsModel: B=64 N=32 H=W=16 A=16 K=3 stride=2 -> Ho=Wo=7, M=32, SD=4, D=16
// conv routing: 2 sites/block, 256 thr (32 m-lanes x 8 nkl-groups),
//   2 sites per thread. Design point: VGPR <= 128 (gfx950 wave slots halve
//   above 128 -> R7's 136 VGPR gave 1 block/CU), zero spills, LDS 31.5 KB
//   (s_inp + wT in bf16, vc read from LDS, 2-stage s_red) -> 4 blocks/CU.
// fc routing: pass-split kernels (unchanged from R7).

#define LN_EPS 1e-5f

__device__ __forceinline__ unsigned bf16rne(float f) {
    unsigned u = __float_as_uint(f);
    return (u + 0x7fffu + ((u >> 16) & 1u)) >> 16;
}
__device__ __forceinline__ float bfLO(unsigned u) { return __uint_as_float(u << 16); }
__device__ __forceinline__ float bfHI(unsigned u) { return __uint_as_float(u & 0xffff0000u); }

// ---------------- weight transposes ----------------
// wTb [288][32][16] bf16: row r = n*9+kl, wTb[(r*32+m)*16+xd]
__global__ __launch_bounds__(256) void transpose_wconv(
    const float* __restrict__ wconv, unsigned short* __restrict__ wTb)
{
    const int i = blockIdx.x * 256 + threadIdx.x;
    if (i < 147456) {
        const int xd = i & 15, mm = (i >> 4) & 31, r = i >> 9;   // r = n*9+kl
        const int n = r / 9, kl = r % 9;
        wTb[i] = (unsigned short)bf16rne(wconv[((kl * 32 + n) * 16 + xd) * 32 + mm]);
    }
}

// wT2b [1568][16][16] fp32: [n][m (pad 10->16, zeros)][x*4+d]
__global__ __launch_bounds__(256) void transpose_wfc(
    const float* __restrict__ wfc, float* __restrict__ wT2b)
{
    const int j = blockIdx.x * 256 + threadIdx.x;
    if (j < 401408) {
        const int xd = j & 15, mm = (j >> 4) & 15, n = j >> 8;
        const int x = xd >> 2, dd = xd & 3;
        wT2b[j] = (mm < 10) ? wfc[((n * 4 + x) * 4 + dd) * 10 + mm] : 0.f;
    }
}

// ---------------- Stage 1: conv routing ----------------
__global__ __launch_bounds__(256, 4) void conv_routing_kernel(
    const float* __restrict__ x,             // [64][32][16][16][16]
    const unsigned short* __restrict__ wTb,  // [288][32][16] bf16
    const float* __restrict__ ln1g,
    const float* __restrict__ ln1b,
    const int*   __restrict__ nroute,
    float* __restrict__ vout)                // [64][32][49][16]
{
    __shared__ unsigned short s_inp[2][288][16];  // bf16, 18,432 B
    __shared__ float s_v[2][32][17];              // 4,352 B (17-pad: scalar conflict-free)
    __shared__ float s_red[2][2][32][17];         // 8,704 B

    const int tid   = threadIdx.x;
    const int m     = tid & 31;
    const int g     = tid >> 5;         // 0..7
    const int wvi   = tid >> 6;         // 0..3
    const int half  = (tid >> 5) & 1;   // which half-wave
    const int site0 = blockIdx.x * 2;

    // stage inp (coalesced float4 loads, bf16 RNE pack)
    for (int i = tid; i < 2304; i += 256) {     // 2 sites * 288 rows * 4 quads
        const int s = (i >= 1152) ? 1 : 0;
        const int j = s ? i - 1152 : i;
        const int row = j >> 2, q = j & 3;
        const int site = site0 + s;
        const int b = site / 49, hw = site % 49;
        const int h = hw / 7, w = hw % 7;
        const int n = row / 9, kl = row % 9;
        const int k = kl / 3, l = kl % 3;
        const float4 val = *(const float4*)(
            x + ((((b * 32 + n) * 16 + (2 * h + k)) * 16 + (2 * w + l)) * 16 + q * 4));
        uint2 p;
        p.x = bf16rne(val.x) | (bf16rne(val.y) << 16);
        p.y = bf16rne(val.z) | (bf16rne(val.w) << 16);
        *(uint2*)(&s_inp[s][row][q * 4]) = p;
    }
    __syncthreads();

    const int R = *nroute;
    const int nkl0 = g * 36;
    const unsigned short* const wp0 = wTb + (nkl0 * 32 + m) * 16;

    for (int pass = 0; pass < R; ++pass) {
        float vn0[16], vn1[16];
#pragma unroll
        for (int i = 0; i < 16; ++i) { vn0[i] = 0.f; vn1[i] = 0.f; }

        // one body: unpack w once, process both sites
        auto body = [&](int t, const unsigned* wu, int routing) {
            const int nkl = nkl0 + t;
            float wv[16];
#pragma unroll
            for (int q = 0; q < 8; ++q) { wv[2 * q] = bfLO(wu[q]); wv[2 * q + 1] = bfHI(wu[q]); }
#pragma unroll
            for (int s = 0; s < 2; ++s) {
                const uint4* rp = (const uint4*)(&s_inp[s][nkl][0]);
                const uint4 ua = rp[0], ub = rp[1];
                float in_[16];
                in_[0] = bfLO(ua.x);  in_[1] = bfHI(ua.x);
                in_[2] = bfLO(ua.y);  in_[3] = bfHI(ua.y);
                in_[4] = bfLO(ua.z);  in_[5] = bfHI(ua.z);
                in_[6] = bfLO(ua.w);  in_[7] = bfHI(ua.w);
                in_[8] = bfLO(ub.x);  in_[9] = bfHI(ub.x);
                in_[10] = bfLO(ub.y); in_[11] = bfHI(ub.y);
                in_[12] = bfLO(ub.z); in_[13] = bfHI(ub.z);
                in_[14] = bfLO(ub.w); in_[15] = bfHI(ub.w);
                float uh[16];
#pragma unroll
                for (int a = 0; a < 4; ++a) {
#pragma unroll
                    for (int d = 0; d < 4; ++d) {
                        float acc = in_[a * 4 + 0] * wv[0 + d];
                        acc = fmaf(in_[a * 4 + 1], wv[4 + d], acc);
                        acc = fmaf(in_[a * 4 + 2], wv[8 + d], acc);
                        acc = fmaf(in_[a * 4 + 3], wv[12 + d], acc);
                        uh[a * 4 + d] = acc;
                    }
                }
                float* vn = s ? vn1 : vn0;
                if (!routing) {
#pragma unroll
                    for (int i = 0; i < 16; ++i) vn[i] += uh[i];
                } else {
                    const float* vcp = &s_v[s][m][0];   // conflict-free (17-pad)
                    float l0 = uh[0] * vcp[0], l1 = uh[1] * vcp[1];
                    float l2 = uh[2] * vcp[2], l3 = uh[3] * vcp[3];
#pragma unroll
                    for (int i = 4; i < 16; i += 4) {
                        l0 = fmaf(uh[i + 0], vcp[i + 0], l0);
                        l1 = fmaf(uh[i + 1], vcp[i + 1], l1);
                        l2 = fmaf(uh[i + 2], vcp[i + 2], l2);
                        l3 = fmaf(uh[i + 3], vcp[i + 3], l3);
                    }
                    const float lg = ((l0 + l1) + (l2 + l3)) * 0.25f;
                    const float e = __expf(lg);
                    float sm = e;
#pragma unroll
                    for (int off = 16; off >= 1; off >>= 1)
                        sm += __shfl_xor(sm, off, 32);
                    const float qk = e * __builtin_amdgcn_rcpf(sm * (1.f + 1e-10f));
#pragma unroll
                    for (int i = 0; i < 16; ++i) vn[i] = fmaf(qk, uh[i], vn[i]);
                }
            }
        };

        // K-loop: unroll 2, double-buffered bf16 w prefetch (8 uints per buffer)
        {
            const unsigned short* wp = wp0;
            unsigned wA[8], wB[8];
            *(uint4*)&wA[0] = *(const uint4*)(wp);
            *(uint4*)&wA[4] = *(const uint4*)(wp + 8);
            const int routing = (pass != 0);
            for (int t2 = 0; t2 < 17; ++t2) {
                const int t = t2 * 2;
                *(uint4*)&wB[0] = *(const uint4*)(wp + 512);
                *(uint4*)&wB[4] = *(const uint4*)(wp + 520);
                body(t, wA, routing);
                *(uint4*)&wA[0] = *(const uint4*)(wp + 1024);
                *(uint4*)&wA[4] = *(const uint4*)(wp + 1032);
                body(t + 1, wB, routing);
                wp += 1024;
            }
            *(uint4*)&wB[0] = *(const uint4*)(wp + 512);
            *(uint4*)&wB[4] = *(const uint4*)(wp + 520);
            body(34, wA, routing);
            body(35, wB, routing);
        }

        // pre-reduce the 2 g's within each wave (both halves end with totals)
#pragma unroll
        for (int i = 0; i < 16; ++i) {
            vn0[i] += __shfl_xor(vn0[i], 32, 64);
            vn1[i] += __shfl_xor(vn1[i], 32, 64);
        }
        // per-lane site role: lower half owns site0 (vn0), upper half site1 (vn1)
        float* vsel = half ? vn1 : vn0;
        const int sst = half;

        if (wvi >= 2) {
            const int slot = wvi - 2;
#pragma unroll
            for (int i = 0; i < 16; ++i) s_red[slot][sst][m][i] = vsel[i];
        }
        __syncthreads();
        if (wvi < 2) {
#pragma unroll
            for (int i = 0; i < 16; ++i) vsel[i] += s_red[wvi][sst][m][i];
            if (wvi == 1) {
#pragma unroll
                for (int i = 0; i < 16; ++i) s_red[1][sst][m][i] = vsel[i];
            }
        }
        __syncthreads();
        if (wvi == 0) {
#pragma unroll
            for (int i = 0; i < 16; ++i) vsel[i] += s_red[1][sst][m][i];
            const float scale = pass ? 1.f : (1.f / 32.f);
            float mu = 0.f;
#pragma unroll
            for (int i = 0; i < 16; ++i) { vsel[i] *= scale; mu += vsel[i]; }
            mu *= (1.f / 16.f);
            float var = 0.f;
#pragma unroll
            for (int i = 0; i < 16; ++i) {
                const float d0 = vsel[i] - mu;
                var = fmaf(d0, d0, var);
            }
            var *= (1.f / 16.f);
            const float inv = rsqrtf(var + LN_EPS);
#pragma unroll
            for (int i = 0; i < 16; ++i)
                s_v[sst][m][i] = (vsel[i] - mu) * inv * ln1g[i] + ln1b[i];
        }
        __syncthreads();
    }

    // write v (scalar, coalesced in 16-elem runs)
    for (int p = tid; p < 1024; p += 256) {
        const int s = p >> 9, mm = (p >> 4) & 31, i = p & 15;
        const int site = site0 + s;
        const int b = site / 49, hw = site % 49;
        vout[((b * 32 + mm) * 49 + hw) * 16 + i] = s_v[s][mm][i];
    }
}

// ---------------- Stage 2: FC routing (pass-split, unchanged) ----------------
__global__ __launch_bounds__(256, 4) void fc_partial(
    const float* __restrict__ fcin,  // [64][1568][16]
    const float* __restrict__ wT2b,  // [1568][16][16] ([n][ml][x*4+d])
    const float* __restrict__ u,     // [64][16][16]
    const int*   __restrict__ nroute,
    const int    pass,
    float* __restrict__ partial)     // [512][16][16]
{
    __shared__ float s_red[4][16][17];

    const int R = *nroute;
    if (pass >= R) return;
    const int blk = blockIdx.x;
    const int b = blk >> 3, c = blk & 7;
    const int tid = threadIdx.x;
    const int ml = tid & 15, grp = tid >> 4;
    const int wv = tid >> 6;
    const float* fb = fcin + (b * 1568 + c * 196) * 16;
    const float* wb = wT2b + (c * 196 * 16) * 16;

    float un[16];
#pragma unroll
    for (int i = 0; i < 16; ++i) un[i] = 0.f;
    float ur[16];
    if (pass) {
#pragma unroll
        for (int q = 0; q < 4; ++q)
            *(float4*)(&ur[q * 4]) = *(const float4*)(u + (b * 16 + ml) * 16 + q * 4);
    }

    for (int t = 0; t < 13; ++t) {
        const int off = t * 16 + grp;
        if (off >= 196) break;
        float iv[16], wv_[16];
        const float* ip = fb + off * 16;
        const float* wp = wb + (off * 16 + ml) * 16;
#pragma unroll
        for (int q = 0; q < 4; ++q) {
            *(float4*)(&iv[q * 4]) = *(const float4*)(ip + q * 4);
            *(float4*)(&wv_[q * 4]) = *(const float4*)(wp + q * 4);
        }
        float vote[16];
#pragma unroll
        for (int a = 0; a < 4; ++a) {
#pragma unroll
            for (int d = 0; d < 4; ++d) {
                float acc = iv[a * 4 + 0] * wv_[0 + d];
                acc = fmaf(iv[a * 4 + 1], wv_[4 + d], acc);
                acc = fmaf(iv[a * 4 + 2], wv_[8 + d], acc);
                acc = fmaf(iv[a * 4 + 3], wv_[12 + d], acc);
                vote[a * 4 + d] = acc;
            }
        }
        if (pass == 0) {
#pragma unroll
            for (int i = 0; i < 16; ++i) un[i] += vote[i];
        } else {
            float l0 = vote[0] * ur[0], l1 = vote[1] * ur[1];
            float l2 = vote[2] * ur[2], l3 = vote[3] * ur[3];
#pragma unroll
            for (int i = 4; i < 16; i += 4) {
                l0 = fmaf(vote[i + 0], ur[i + 0], l0);
                l1 = fmaf(vote[i + 1], ur[i + 1], l1);
                l2 = fmaf(vote[i + 2], ur[i + 2], l2);
                l3 = fmaf(vote[i + 3], ur[i + 3], l3);
            }
            const float lg = ((l0 + l1) + (l2 + l3)) * 0.25f;
            float e = __expf(lg);
            if (ml >= 10) e = 0.f;
            float sm = e;
#pragma unroll
            for (int off2 = 8; off2 >= 1; off2 >>= 1)
                sm += __shfl_xor(sm, off2, 16);
            const float qk = e * __builtin_amdgcn_rcpf(sm * (1.f + 1e-10f));
#pragma unroll
            for (int i = 0; i < 16; ++i) un[i] = fmaf(qk, vote[i], un[i]);
        }
    }

#pragma unroll
    for (int i = 0; i < 16; ++i) {
        un[i] += __shfl_xor(un[i], 16, 64);
        un[i] += __shfl_xor(un[i], 32, 64);
    }
    if ((tid & 63) < 16) {
#pragma unroll
        for (int i = 0; i < 16; ++i) s_red[wv][ml][i] = un[i];
    }
    __syncthreads();
    {
        const int mlf = tid >> 4, i = tid & 15;
        const float s = s_red[0][mlf][i] + s_red[1][mlf][i]
                      + s_red[2][mlf][i] + s_red[3][mlf][i];
        partial[(blk * 16 + mlf) * 16 + i] = s;
    }
}

__global__ __launch_bounds__(256) void fc_combine(
    const float* __restrict__ partial,  // [512][16][16]
    const float* __restrict__ ln2g,
    const float* __restrict__ ln2b,
    const int*   __restrict__ nroute,
    const int    pass,
    float* __restrict__ u,              // [64][16][16]
    float* __restrict__ out)            // [64][10][16]
{
    const int R = *nroute;
    if (pass >= R) return;
    const int b = blockIdx.x;
    const int tid = threadIdx.x;
    const int i = tid & 15, ml = tid >> 4;

    float s = 0.f;
#pragma unroll
    for (int c = 0; c < 8; ++c)
        s += partial[((b * 8 + c) * 16 + ml) * 16 + i];
    if (pass == 0) s *= 0.1f;

    float mu = s;
#pragma unroll
    for (int off = 8; off >= 1; off >>= 1) mu += __shfl_xor(mu, off, 16);
    mu *= (1.f / 16.f);
    const float d0 = s - mu;
    float var = d0 * d0;
#pragma unroll
    for (int off = 8; off >= 1; off >>= 1) var += __shfl_xor(var, off, 16);
    var *= (1.f / 16.f);
    const float r = (s - mu) * rsqrtf(var + LN_EPS) * ln2g[i] + ln2b[i];

    u[(b * 16 + ml) * 16 + i] = r;
    if (pass == R - 1 && ml < 10) out[(b * 10 + ml) * 16 + i] = r;
}

extern "C" void kernel_launch(void* const* d_in, const int* in_sizes, int n_in,
                              void* d_out, int out_size, void* d_ws, size_t ws_size,
                              hipStream_t stream) {
    const float* x     = (const float*)d_in[0];
    const float* wconv = (const float*)d_in[1];
    const float* wfc   = (const float*)d_in[2];
    const float* ln1g  = (const float*)d_in[3];
    const float* ln1b  = (const float*)d_in[4];
    const float* ln2g  = (const float*)d_in[5];
    const float* ln2b  = (const float*)d_in[6];
    const int*   nrt   = (const int*)d_in[7];

    float* vout = (float*)d_ws;                                  // 6,422,528 B
    // wTb (294,912 B bf16) and wT2b (1,605,632 B fp32) share this region:
    // transpose_wfc runs AFTER conv_routing_kernel consumed wTb.
    unsigned short* wTb = (unsigned short*)((char*)d_ws + 6422528);
    float* wT2b    = (float*)((char*)d_ws + 6422528);
    float* ubuf    = (float*)((char*)d_ws + 8028160);            // 65,536 B
    float* partial = (float*)((char*)d_ws + 8093696);            // 524,288 B
    float* out     = (float*)d_out;

    hipLaunchKernelGGL(transpose_wconv, dim3(576), dim3(256), 0, stream,
                       wconv, wTb);
    hipLaunchKernelGGL(conv_routing_kernel, dim3(1568), dim3(256), 0, stream,
                       x, wTb, ln1g, ln1b, nrt, vout);
    hipLaunchKernelGGL(transpose_wfc, dim3(1568), dim3(256), 0, stream,
                       wfc, wT2b);
    for (int pass = 0; pass < 3; ++pass) {
        hipLaunchKernelGGL(fc_partial, dim3(512), dim3(256), 0, stream,
                           vout, wT2b, ubuf, nrt, pass, partial);
        hipLaunchKernelGGL(fc_combine, dim3(64), dim3(256), 0, stream,
                           partial, ln2g, ln2b, nrt, pass, ubuf, out);
    }
}